// Round 8
// baseline (1016.849 us; speedup 1.0000x reference)
//
#include <hip/hip_runtime.h>
#include <stdint.h>

#define BB 8
#define NN 8192
#define NPOINT 1024
#define NSAMPLE 32
#define XS 104   // x row stride in bf16 elems (cols: 0..63 feat, 64..66 xyz, 67..95 zero)
#define HS 72    // h / w2 / w3 row stride in bf16 elems (cols 0..63 used)

typedef short short8 __attribute__((ext_vector_type(8)));
typedef float floatx4 __attribute__((ext_vector_type(4)));
typedef float f32x2 __attribute__((ext_vector_type(2)));

__device__ __forceinline__ unsigned short f2bf(float f) {
    unsigned u = __float_as_uint(f);
    unsigned r = u + 0x7FFFu + ((u >> 16) & 1u);   // RNE to bf16
    return (unsigned short)(r >> 16);
}

__device__ __forceinline__ unsigned long long u64max(unsigned long long a,
                                                     unsigned long long b) {
    return (a > b) ? a : b;
}

template <int CTRL, int RMASK>
__device__ __forceinline__ unsigned long long dpp_max_step(unsigned long long key) {
    int lo = (int)(unsigned int)(key & 0xffffffffull);
    int hi = (int)(unsigned int)(key >> 32);
    int tlo = __builtin_amdgcn_update_dpp(0, lo, CTRL, RMASK, 0xF, true);
    int thi = __builtin_amdgcn_update_dpp(0, hi, CTRL, RMASK, 0xF, true);
    unsigned long long t = ((unsigned long long)(unsigned int)thi << 32) |
                           (unsigned long long)(unsigned int)tlo;
    return u64max(key, t);
}

__device__ __forceinline__ unsigned long long dpp_wave_max(unsigned long long key) {
    key = dpp_max_step<0x111, 0xF>(key);  // row_shr:1
    key = dpp_max_step<0x112, 0xF>(key);  // row_shr:2
    key = dpp_max_step<0x114, 0xF>(key);  // row_shr:4
    key = dpp_max_step<0x118, 0xF>(key);  // row_shr:8
    key = dpp_max_step<0x142, 0xA>(key);  // row_bcast:15
    key = dpp_max_step<0x143, 0xC>(key);  // row_bcast:31
    return key;
}

// Barrier that does NOT drain vmcnt: LDS ordering only (measured neutral vs
// __syncthreads in R11; kept because it cannot be slower).
__device__ __forceinline__ void fps_bar() {
    asm volatile("s_waitcnt lgkmcnt(0)" ::: "memory");
    __builtin_amdgcn_s_barrier();
    asm volatile("" ::: "memory");
}

// ---------------------------------------------------------------------------
// MEGA KERNEL (256-thread blocks). Blocks 0..7: FPS (one per batch, 4 waves,
// 32 pts/thread). Blocks 8..2055: consumers (b=i&7, g=i>>3), 4 centroids each.
//
// R14: SCLK probe. The FPS serial path is modeled at ~1000 cy/iter but
// measures 2210 cy/iter @2.4GHz-nominal, robust to every instruction-level
// edit (R8-R13). Hypothesis: the chip spends ~97% of the kernel in
// s_sleep-dominated spin (VALUBusy 6%) and DPM holds SCLK well below boost;
// the "extra" cycles are a clock-denominator artifact. Probe: consumer wait
// becomes a busy VALU burn (dependent LCG, asm-sink kept live) on ALL 4
// waves of every waiting block, with 4 threads polling sel[] and posting an
// LDS ready-count. Chip VALUBusy should jump >50% (activation check).
// FPS path = unchanged champion (R11/R13 structure).
// Pre-committed read: ~550-700us => clock was the factor; >1000us =>
// power-throttle (revert); ~943us => hypothesis dead, serial floor is real.
// ---------------------------------------------------------------------------
__global__ __launch_bounds__(256) void mega_kernel(
    const float* __restrict__ xyz, const float* __restrict__ features,
    const float* __restrict__ w1, const float* __restrict__ b1,
    const float* __restrict__ w2, const float* __restrict__ b2,
    const float* __restrict__ w3, const float* __restrict__ b3,
    float* __restrict__ new_xyz, float* __restrict__ out_feat,
    unsigned* __restrict__ sel) {
    __shared__ __align__(16) char smem[98432];

    const int t = threadIdx.x;
    const int lane = t & 63;

    if (blockIdx.x < BB) {
        // =================== FPS (4 waves, u64-key DPP reduce) ==============
#pragma clang fp contract(off)
        const int b = blockIdx.x;
        float* sxyz = (float*)smem;                              // [8192][3]
        unsigned long long* wred = (unsigned long long*)(smem + 98304); // [2][4]
        const int wv = t >> 6;
        const float* base = xyz + (size_t)b * NN * 3;
        unsigned* selb = sel + b * NPOINT;

        f32x2 px2[16], py2[16], pz2[16];
        float dist[32];
#pragma unroll
        for (int i = 0; i < 32; ++i) {
            int p = t + (i << 8);               // coalesced glb; LDS 2-way/bank
            float x = base[p * 3 + 0];
            float y = base[p * 3 + 1];
            float z = base[p * 3 + 2];
            sxyz[p * 3 + 0] = x; sxyz[p * 3 + 1] = y; sxyz[p * 3 + 2] = z;
            if (i & 1) { px2[i >> 1].y = x; py2[i >> 1].y = y; pz2[i >> 1].y = z; }
            else       { px2[i >> 1].x = x; py2[i >> 1].x = y; pz2[i >> 1].x = z; }
            dist[i] = 1e10f;                    // f32(10000000000.0) exact
        }
        __syncthreads();

        float lx = sxyz[0], ly = sxyz[1], lz = sxyz[2];
        float* outb = new_xyz + (size_t)b * NPOINT * 3;
        if (t == 0) {
            outb[0] = lx; outb[1] = ly; outb[2] = lz;
            __hip_atomic_store(&selb[0], 1u, __ATOMIC_RELAXED,
                               __HIP_MEMORY_SCOPE_AGENT);
        }

        for (int j = 1; j < NPOINT; ++j) {
            float bd0 = -1.0f, bd1 = -1.0f;
            int bi0 = 0, bi1 = 16;
            f32x2 lx2; lx2.x = lx; lx2.y = lx;
            f32x2 ly2; ly2.x = ly; ly2.y = ly;
            f32x2 lz2; lz2.x = lz; lz2.y = lz;
#pragma unroll
            for (int jj = 0; jj < 16; ++jj) {
                // packed (v_pk_add_f32 / v_pk_mul_f32, IEEE RN, no contraction)
                f32x2 dx = px2[jj] - lx2;
                f32x2 dy = py2[jj] - ly2;
                f32x2 dz = pz2[jj] - lz2;
                f32x2 xx = dx * dx;
                f32x2 yy = dy * dy;
                f32x2 zz = dz * dz;
                f32x2 s1 = xx + yy;
                f32x2 d2 = s1 + zz;
                float d0 = fminf(dist[2 * jj], d2.x);
                dist[2 * jj] = d0;
                float d1 = fminf(dist[2 * jj + 1], d2.y);
                dist[2 * jj + 1] = d1;
                // within-pair argmax: >= prefers even slot (lower point idx)
                bool ge = d0 >= d1;
                float pm = ge ? d0 : d1;
                int pi = ge ? (2 * jj) : (2 * jj + 1);
                if (jj < 8) {            // chain A: elems 0..15 (lower indices)
                    bool gt = pm > bd0;
                    bd0 = gt ? pm : bd0;
                    bi0 = gt ? pi : bi0;
                } else {                 // chain B: elems 16..31
                    bool gt = pm > bd1;
                    bd1 = gt ? pm : bd1;
                    bi1 = gt ? pi : bi1;
                }
            }
            unsigned long long key0 =
                ((unsigned long long)__float_as_uint(bd0) << 32) |
                (unsigned long long)(~(unsigned int)(t + (bi0 << 8)));
            unsigned long long key1 =
                ((unsigned long long)__float_as_uint(bd1) << 32) |
                (unsigned long long)(~(unsigned int)(t + (bi1 << 8)));
            unsigned long long key = u64max(key0, key1);
            key = dpp_wave_max(key);
            if (lane == 63) wred[(j & 1) * 4 + wv] = key;
            fps_bar();
            int cur;
            {
                const unsigned long long* wr = &wred[(j & 1) * 4];
                ulonglong2 p01 = *(const ulonglong2*)&wr[0];
                ulonglong2 p23 = *(const ulonglong2*)&wr[2];
                unsigned long long m = u64max(u64max(p01.x, p01.y),
                                              u64max(p23.x, p23.y));
                cur = (int)(~(unsigned int)(m & 0xffffffffull));
            }
            {   // one contiguous 12B broadcast read (wave-uniform address)
                const float* cp = &sxyz[cur * 3];
                float3 c = *(const float3*)cp;
                lx = c.x; ly = c.y; lz = c.z;
            }
            if (t == 0) {
                outb[j * 3 + 0] = lx;
                outb[j * 3 + 1] = ly;
                outb[j * 3 + 2] = lz;
                __hip_atomic_store(&selb[j], (unsigned)(cur + 1),
                                   __ATOMIC_RELAXED, __HIP_MEMORY_SCOPE_AGENT);
            }
        }
    } else {
        // =================== consumer: ballq + MFMA MLP =====================
        const int i = blockIdx.x - BB;
        const int b = i & 7;                   // batch
        const int g = i >> 3;                  // centroid group (4 centroids)
        unsigned short* s_x = (unsigned short*)smem;            // 128*XS
        unsigned short* s_h = (unsigned short*)(smem + 26624);  // 128*HS
        unsigned short* s_w12 = (unsigned short*)(smem + 45056);// 11264 elems
        int* s_gi = (int*)(smem + 67584);                       // 128
        int* s_sel4 = (int*)(smem + 68096);                     // 4
        int* s_ready = (int*)(smem + 68112);                    // 1

        const int w = t >> 6;
        const int col = lane & 15;
        const int quad = lane >> 4;

        // ready-count must be zeroed BEFORE any poller can increment (late
        // blocks may find sel[] already published) -> barrier-ordered.
        if (t == 0) *s_ready = 0;
        __syncthreads();

        // ---- stage w1, w2 (independent of fps progress) ----
        {
            int o = t >> 2, part = t & 3;
            const float* w1r = w1 + o * 67;
#pragma unroll
            for (int ii = 0; ii < 26; ++ii) {
                int c = part * 26 + ii;
                float v = 0.0f;
                if (c < 64) v = w1r[3 + c];           // permuted: feats first
                else if (c < 67) v = w1r[c - 64];     // then xyz cols
                s_w12[o * XS + c] = f2bf(v);
            }
            const float* w2r = w2 + o * 64 + part * 16;
#pragma unroll
            for (int ii = 0; ii < 8; ++ii) {
                unsigned pk = (unsigned)f2bf(w2r[2 * ii]) |
                              ((unsigned)f2bf(w2r[2 * ii + 1]) << 16);
                *(unsigned*)&s_w12[6656 + o * HS + part * 16 + 2 * ii] = pk;
            }
        }

        // ---- busy-wait for the 4 centroid indices (keeps SCLK up) ----
        unsigned lcg = 0x9E3779B9u + (unsigned)t;
        if (t < 4) {
            unsigned* sp = sel + b * NPOINT + (g << 2) + t;
            for (;;) {
                unsigned v = __hip_atomic_load(sp, __ATOMIC_RELAXED,
                                               __HIP_MEMORY_SCOPE_AGENT);
                if ((v - 1u) <= 8191u) { s_sel4[t] = (int)(v - 1u); break; }
#pragma unroll
                for (int q = 0; q < 16; ++q)
                    lcg = lcg * 1664525u + 1013904223u;
                asm volatile("" :: "v"(lcg));   // keep burn live (no DCE)
            }
            __hip_atomic_fetch_add(s_ready, 1, __ATOMIC_RELAXED,
                                   __HIP_MEMORY_SCOPE_WORKGROUP);
        }
        // all waves burn VALU until the 4 indices are posted
        while (__hip_atomic_load(s_ready, __ATOMIC_RELAXED,
                                 __HIP_MEMORY_SCOPE_WORKGROUP) < 4) {
#pragma unroll
            for (int q = 0; q < 16; ++q)
                lcg = lcg * 1664525u + 1013904223u;
            asm volatile("" :: "v"(lcg));       // keep burn live (no DCE)
        }
        __syncthreads();

        // ---- ball query: wave w -> centroid s_sel4[w] ----
        {
            const int cidx = s_sel4[w];
            const float* base = xyz + (size_t)b * NN * 3;
            const float cx = base[cidx * 3 + 0];   // bit-identical to new_xyz
            const float cy = base[cidx * 3 + 1];
            const float cz = base[cidx * 3 + 2];
            const float R2 = (float)(0.4 * 0.4);   // 0.15999999642f

            int have = 0;
            for (int chunk = 0; chunk < (NN / 64) && have < NSAMPLE; ++chunk) {
                int p = (chunk << 6) + lane;
                float dx = __fsub_rn(cx, base[p * 3 + 0]);
                float dy = __fsub_rn(cy, base[p * 3 + 1]);
                float dz = __fsub_rn(cz, base[p * 3 + 2]);
                float d2 = __fadd_rn(__fadd_rn(__fmul_rn(dx, dx), __fmul_rn(dy, dy)),
                                     __fmul_rn(dz, dz));
                bool in = d2 < R2;
                unsigned long long m = __ballot(in);
                int pre = __popcll(m & ((1ull << lane) - 1ull));
                int slot = have + pre;
                if (in && slot < NSAMPLE) s_gi[w * NSAMPLE + slot] = p;
                have += (int)__popcll(m);
            }
            if (lane < NSAMPLE) {
                int first = s_gi[w * NSAMPLE];    // centroid always hits
                int v = (lane < have) ? s_gi[w * NSAMPLE + lane] : first;
                s_gi[w * NSAMPLE + lane] = v;
            }
        }
        __syncthreads();

        // ---- gather x = [feat(64) | xyz_rel(3) | zeros] in bf16 ----
        {
            int k = t >> 1, half = t & 1;
            int row = s_gi[k];
            const float4* frow =
                (const float4*)(features + ((size_t)b * NN + row) * 64) + half * 8;
            unsigned short* xr = &s_x[k * XS + half * 32];
#pragma unroll
            for (int ii = 0; ii < 8; ++ii) {
                float4 v = frow[ii];
                unsigned lo = (unsigned)f2bf(v.x) | ((unsigned)f2bf(v.y) << 16);
                unsigned hi = (unsigned)f2bf(v.z) | ((unsigned)f2bf(v.w) << 16);
                *(uint2*)(xr + ii * 4) = make_uint2(lo, hi);
            }
        }
        if (t < 128) {
            int k = t;
            int row = s_gi[k];
            int cidx = s_sel4[k >> 5];
            const float* pr = xyz + ((size_t)b * NN + row) * 3;
            const float* cr = xyz + ((size_t)b * NN + cidx) * 3;
            s_x[k * XS + 64] = f2bf(pr[0] - cr[0]);
            s_x[k * XS + 65] = f2bf(pr[1] - cr[1]);
            s_x[k * XS + 66] = f2bf(pr[2] - cr[2]);
            s_x[k * XS + 67] = 0;
            unsigned* z = (unsigned*)&s_x[k * XS + 68];
#pragma unroll
            for (int ii = 0; ii < 14; ++ii) z[ii] = 0;    // cols 68..95
        }
        __syncthreads();

        const int mbase = w * 32;

        // ---- Layer 1: [128 x 96] x [96 -> 64] ----
        floatx4 acc[2][4] = {};
        for (int kk = 0; kk < 3; ++kk) {
            short8 a0 = *(const short8*)&s_x[(mbase + col) * XS + kk * 32 + quad * 8];
            short8 a1 = *(const short8*)&s_x[(mbase + 16 + col) * XS + kk * 32 + quad * 8];
#pragma unroll
            for (int nt = 0; nt < 4; ++nt) {
                short8 bfr = *(const short8*)&s_w12[(nt * 16 + col) * XS + kk * 32 + quad * 8];
                acc[0][nt] = __builtin_amdgcn_mfma_f32_16x16x32_bf16(a0, bfr, acc[0][nt], 0, 0, 0);
                acc[1][nt] = __builtin_amdgcn_mfma_f32_16x16x32_bf16(a1, bfr, acc[1][nt], 0, 0, 0);
            }
        }
#pragma unroll
        for (int nt = 0; nt < 4; ++nt) {
            float bb = b1[nt * 16 + col];
#pragma unroll
            for (int mt = 0; mt < 2; ++mt)
#pragma unroll
                for (int r = 0; r < 4; ++r) {
                    float v = fmaxf(acc[mt][nt][r] + bb, 0.0f);
                    s_h[(mbase + mt * 16 + quad * 4 + r) * HS + nt * 16 + col] = f2bf(v);
                }
        }
        __syncthreads();

        // ---- Layer 2: [128 x 64] x [64 -> 64], h2 -> s_x region ----
        floatx4 acc2[2][4] = {};
        for (int kk = 0; kk < 2; ++kk) {
            short8 a0 = *(const short8*)&s_h[(mbase + col) * HS + kk * 32 + quad * 8];
            short8 a1 = *(const short8*)&s_h[(mbase + 16 + col) * HS + kk * 32 + quad * 8];
#pragma unroll
            for (int nt = 0; nt < 4; ++nt) {
                short8 bfr = *(const short8*)&s_w12[6656 + (nt * 16 + col) * HS + kk * 32 + quad * 8];
                acc2[0][nt] = __builtin_amdgcn_mfma_f32_16x16x32_bf16(a0, bfr, acc2[0][nt], 0, 0, 0);
                acc2[1][nt] = __builtin_amdgcn_mfma_f32_16x16x32_bf16(a1, bfr, acc2[1][nt], 0, 0, 0);
            }
        }
        unsigned short* s_h2 = s_x;  // x dead after L1
#pragma unroll
        for (int nt = 0; nt < 4; ++nt) {
            float bb = b2[nt * 16 + col];
#pragma unroll
            for (int mt = 0; mt < 2; ++mt)
#pragma unroll
                for (int r = 0; r < 4; ++r) {
                    float v = fmaxf(acc2[mt][nt][r] + bb, 0.0f);
                    s_h2[(mbase + mt * 16 + quad * 4 + r) * HS + nt * 16 + col] = f2bf(v);
                }
        }
        __syncthreads();   // h2 complete; all w2 reads done

        // ---- stage w3 [128][HS] over w1/w2 ----
        {
            int o = t >> 1, half = t & 1;
            const float* w3r = w3 + o * 64 + half * 32;
#pragma unroll
            for (int ii = 0; ii < 16; ++ii) {
                unsigned pk = (unsigned)f2bf(w3r[2 * ii]) |
                              ((unsigned)f2bf(w3r[2 * ii + 1]) << 16);
                *(unsigned*)&s_w12[o * HS + half * 32 + 2 * ii] = pk;
            }
        }
        __syncthreads();

        // ---- Layer 3: [128 x 64] x [64 -> 128], fused maxpool+bias+relu ----
        floatx4 c3[2][8] = {};
        for (int kk = 0; kk < 2; ++kk) {
            short8 a0 = *(const short8*)&s_h2[(mbase + col) * HS + kk * 32 + quad * 8];
            short8 a1 = *(const short8*)&s_h2[(mbase + 16 + col) * HS + kk * 32 + quad * 8];
#pragma unroll
            for (int nt = 0; nt < 8; ++nt) {
                short8 bfr = *(const short8*)&s_w12[(nt * 16 + col) * HS + kk * 32 + quad * 8];
                c3[0][nt] = __builtin_amdgcn_mfma_f32_16x16x32_bf16(a0, bfr, c3[0][nt], 0, 0, 0);
                c3[1][nt] = __builtin_amdgcn_mfma_f32_16x16x32_bf16(a1, bfr, c3[1][nt], 0, 0, 0);
            }
        }
        {
            int gg = (g << 2) + w;
            float* ob = out_feat + (size_t)b * (128 * 1024) + gg;
#pragma unroll
            for (int nt = 0; nt < 8; ++nt) {
                float m = fmaxf(fmaxf(fmaxf(c3[0][nt][0], c3[0][nt][1]),
                                      fmaxf(c3[0][nt][2], c3[0][nt][3])),
                                fmaxf(fmaxf(c3[1][nt][0], c3[1][nt][1]),
                                      fmaxf(c3[1][nt][2], c3[1][nt][3])));
                m = fmaxf(m, __shfl_xor(m, 16));
                m = fmaxf(m, __shfl_xor(m, 32));
                if (lane < 16) {
                    float v = fmaxf(m + b3[nt * 16 + lane], 0.0f);
                    ob[(size_t)(nt * 16 + lane) * 1024] = v;
                }
            }
        }
    }
}

extern "C" void kernel_launch(void* const* d_in, const int* in_sizes, int n_in,
                              void* d_out, int out_size, void* d_ws, size_t ws_size,
                              hipStream_t stream) {
    const float* xyz      = (const float*)d_in[0];
    const float* features = (const float*)d_in[1];
    const float* w1       = (const float*)d_in[2];
    const float* b1       = (const float*)d_in[3];
    const float* w2       = (const float*)d_in[4];
    const float* b2       = (const float*)d_in[5];
    const float* w3       = (const float*)d_in[6];
    const float* b3       = (const float*)d_in[7];

    float* out      = (float*)d_out;
    float* new_xyz  = out;                         // B*NPOINT*3
    float* out_feat = out + BB * NPOINT * 3;       // B*128*NPOINT
    unsigned* sel   = (unsigned*)d_ws;             // B*NPOINT u32; poison = not-ready

    mega_kernel<<<BB + (BB * NPOINT) / 4, 256, 0, stream>>>(
        xyz, features, w1, b1, w2, b2, w3, b3, new_xyz, out_feat, sel);
}

// Round 9
// 1016.380 us; speedup vs baseline: 1.0005x; 1.0005x over previous
//
#include <hip/hip_runtime.h>
#include <stdint.h>

#define BB 8
#define NN 8192
#define NPOINT 1024
#define NSAMPLE 32
#define XS 104   // x row stride in bf16 elems (cols: 0..63 feat, 64..66 xyz, 67..95 zero)
#define HS 72    // h / w2 / w3 row stride in bf16 elems (cols 0..63 used)

typedef short short8 __attribute__((ext_vector_type(8)));
typedef float floatx4 __attribute__((ext_vector_type(4)));
typedef float f32x2 __attribute__((ext_vector_type(2)));

__device__ __forceinline__ unsigned short f2bf(float f) {
    unsigned u = __float_as_uint(f);
    unsigned r = u + 0x7FFFu + ((u >> 16) & 1u);   // RNE to bf16
    return (unsigned short)(r >> 16);
}

__device__ __forceinline__ unsigned long long u64max(unsigned long long a,
                                                     unsigned long long b) {
    return (a > b) ? a : b;
}

template <int CTRL, int RMASK>
__device__ __forceinline__ unsigned long long dpp_max_step(unsigned long long key) {
    int lo = (int)(unsigned int)(key & 0xffffffffull);
    int hi = (int)(unsigned int)(key >> 32);
    int tlo = __builtin_amdgcn_update_dpp(0, lo, CTRL, RMASK, 0xF, true);
    int thi = __builtin_amdgcn_update_dpp(0, hi, CTRL, RMASK, 0xF, true);
    unsigned long long t = ((unsigned long long)(unsigned int)thi << 32) |
                           (unsigned long long)(unsigned int)tlo;
    return u64max(key, t);
}

__device__ __forceinline__ unsigned long long dpp_wave_max(unsigned long long key) {
    key = dpp_max_step<0x111, 0xF>(key);  // row_shr:1
    key = dpp_max_step<0x112, 0xF>(key);  // row_shr:2
    key = dpp_max_step<0x114, 0xF>(key);  // row_shr:4
    key = dpp_max_step<0x118, 0xF>(key);  // row_shr:8
    key = dpp_max_step<0x142, 0xA>(key);  // row_bcast:15
    key = dpp_max_step<0x143, 0xC>(key);  // row_bcast:31
    return key;
}

// Barrier that does NOT drain vmcnt: LDS ordering only (measured neutral vs
// __syncthreads in R11; kept because it cannot be slower).
__device__ __forceinline__ void fps_bar() {
    asm volatile("s_waitcnt lgkmcnt(0)" ::: "memory");
    __builtin_amdgcn_s_barrier();
    asm volatile("" ::: "memory");
}

// ---------------------------------------------------------------------------
// MEGA KERNEL (256-thread blocks). Blocks 0..7: FPS (one per batch, 4 waves,
// 32 pts/thread). Blocks 8..2055: consumers (b=i&7, g=i>>3), 4 centroids each.
//
// R15: SCLK probe v2. R14's burn only reached VALUBusy 10.9% (LDS poll every
// 16 dep-chained int ops => ~20% duty) — the clock hypothesis was never
// tested. This burn: 4 independent packed-f32 FMA chains (v_pk_fma_f32,
// issue-bound via ILP), 64 unrolled steps = 256 instrs (~512 cy) per
// ready-flag poll => ~78% duty/wave, ~55-70% chip VALUBusy expected.
// Chains bounded (converge to kb/(1-ka)); asm sink after loop keeps the
// recurrence live; loop not elidable (atomic-dependent trip count).
// FPS path = unchanged champion (R11/R13 structure).
// Pre-committed read: VALUBusy>=50% & ~550-700us => clock was the factor;
// VALUBusy>=50% & ~945us => clock hypothesis dead (real latency floor);
// >1000us => power throttle, revert; VALUBusy<30% => probe wrong again.
// ---------------------------------------------------------------------------
__global__ __launch_bounds__(256) void mega_kernel(
    const float* __restrict__ xyz, const float* __restrict__ features,
    const float* __restrict__ w1, const float* __restrict__ b1,
    const float* __restrict__ w2, const float* __restrict__ b2,
    const float* __restrict__ w3, const float* __restrict__ b3,
    float* __restrict__ new_xyz, float* __restrict__ out_feat,
    unsigned* __restrict__ sel) {
    __shared__ __align__(16) char smem[98432];

    const int t = threadIdx.x;
    const int lane = t & 63;

    if (blockIdx.x < BB) {
        // =================== FPS (4 waves, u64-key DPP reduce) ==============
#pragma clang fp contract(off)
        const int b = blockIdx.x;
        float* sxyz = (float*)smem;                              // [8192][3]
        unsigned long long* wred = (unsigned long long*)(smem + 98304); // [2][4]
        const int wv = t >> 6;
        const float* base = xyz + (size_t)b * NN * 3;
        unsigned* selb = sel + b * NPOINT;

        f32x2 px2[16], py2[16], pz2[16];
        float dist[32];
#pragma unroll
        for (int i = 0; i < 32; ++i) {
            int p = t + (i << 8);               // coalesced glb; LDS 2-way/bank
            float x = base[p * 3 + 0];
            float y = base[p * 3 + 1];
            float z = base[p * 3 + 2];
            sxyz[p * 3 + 0] = x; sxyz[p * 3 + 1] = y; sxyz[p * 3 + 2] = z;
            if (i & 1) { px2[i >> 1].y = x; py2[i >> 1].y = y; pz2[i >> 1].y = z; }
            else       { px2[i >> 1].x = x; py2[i >> 1].x = y; pz2[i >> 1].x = z; }
            dist[i] = 1e10f;                    // f32(10000000000.0) exact
        }
        __syncthreads();

        float lx = sxyz[0], ly = sxyz[1], lz = sxyz[2];
        float* outb = new_xyz + (size_t)b * NPOINT * 3;
        if (t == 0) {
            outb[0] = lx; outb[1] = ly; outb[2] = lz;
            __hip_atomic_store(&selb[0], 1u, __ATOMIC_RELAXED,
                               __HIP_MEMORY_SCOPE_AGENT);
        }

        for (int j = 1; j < NPOINT; ++j) {
            float bd0 = -1.0f, bd1 = -1.0f;
            int bi0 = 0, bi1 = 16;
            f32x2 lx2; lx2.x = lx; lx2.y = lx;
            f32x2 ly2; ly2.x = ly; ly2.y = ly;
            f32x2 lz2; lz2.x = lz; lz2.y = lz;
#pragma unroll
            for (int jj = 0; jj < 16; ++jj) {
                // packed (v_pk_add_f32 / v_pk_mul_f32, IEEE RN, no contraction)
                f32x2 dx = px2[jj] - lx2;
                f32x2 dy = py2[jj] - ly2;
                f32x2 dz = pz2[jj] - lz2;
                f32x2 xx = dx * dx;
                f32x2 yy = dy * dy;
                f32x2 zz = dz * dz;
                f32x2 s1 = xx + yy;
                f32x2 d2 = s1 + zz;
                float d0 = fminf(dist[2 * jj], d2.x);
                dist[2 * jj] = d0;
                float d1 = fminf(dist[2 * jj + 1], d2.y);
                dist[2 * jj + 1] = d1;
                // within-pair argmax: >= prefers even slot (lower point idx)
                bool ge = d0 >= d1;
                float pm = ge ? d0 : d1;
                int pi = ge ? (2 * jj) : (2 * jj + 1);
                if (jj < 8) {            // chain A: elems 0..15 (lower indices)
                    bool gt = pm > bd0;
                    bd0 = gt ? pm : bd0;
                    bi0 = gt ? pi : bi0;
                } else {                 // chain B: elems 16..31
                    bool gt = pm > bd1;
                    bd1 = gt ? pm : bd1;
                    bi1 = gt ? pi : bi1;
                }
            }
            unsigned long long key0 =
                ((unsigned long long)__float_as_uint(bd0) << 32) |
                (unsigned long long)(~(unsigned int)(t + (bi0 << 8)));
            unsigned long long key1 =
                ((unsigned long long)__float_as_uint(bd1) << 32) |
                (unsigned long long)(~(unsigned int)(t + (bi1 << 8)));
            unsigned long long key = u64max(key0, key1);
            key = dpp_wave_max(key);
            if (lane == 63) wred[(j & 1) * 4 + wv] = key;
            fps_bar();
            int cur;
            {
                const unsigned long long* wr = &wred[(j & 1) * 4];
                ulonglong2 p01 = *(const ulonglong2*)&wr[0];
                ulonglong2 p23 = *(const ulonglong2*)&wr[2];
                unsigned long long m = u64max(u64max(p01.x, p01.y),
                                              u64max(p23.x, p23.y));
                cur = (int)(~(unsigned int)(m & 0xffffffffull));
            }
            {   // one contiguous 12B broadcast read (wave-uniform address)
                const float* cp = &sxyz[cur * 3];
                float3 c = *(const float3*)cp;
                lx = c.x; ly = c.y; lz = c.z;
            }
            if (t == 0) {
                outb[j * 3 + 0] = lx;
                outb[j * 3 + 1] = ly;
                outb[j * 3 + 2] = lz;
                __hip_atomic_store(&selb[j], (unsigned)(cur + 1),
                                   __ATOMIC_RELAXED, __HIP_MEMORY_SCOPE_AGENT);
            }
        }
    } else {
        // =================== consumer: ballq + MFMA MLP =====================
        const int i = blockIdx.x - BB;
        const int b = i & 7;                   // batch
        const int g = i >> 3;                  // centroid group (4 centroids)
        unsigned short* s_x = (unsigned short*)smem;            // 128*XS
        unsigned short* s_h = (unsigned short*)(smem + 26624);  // 128*HS
        unsigned short* s_w12 = (unsigned short*)(smem + 45056);// 11264 elems
        int* s_gi = (int*)(smem + 67584);                       // 128
        int* s_sel4 = (int*)(smem + 68096);                     // 4
        int* s_ready = (int*)(smem + 68112);                    // 1

        const int w = t >> 6;
        const int col = lane & 15;
        const int quad = lane >> 4;

        // ready-count must be zeroed BEFORE any poller can increment (late
        // blocks may find sel[] already published) -> barrier-ordered.
        if (t == 0) *s_ready = 0;
        __syncthreads();

        // ---- stage w1, w2 (independent of fps progress) ----
        {
            int o = t >> 2, part = t & 3;
            const float* w1r = w1 + o * 67;
#pragma unroll
            for (int ii = 0; ii < 26; ++ii) {
                int c = part * 26 + ii;
                float v = 0.0f;
                if (c < 64) v = w1r[3 + c];           // permuted: feats first
                else if (c < 67) v = w1r[c - 64];     // then xyz cols
                s_w12[o * XS + c] = f2bf(v);
            }
            const float* w2r = w2 + o * 64 + part * 16;
#pragma unroll
            for (int ii = 0; ii < 8; ++ii) {
                unsigned pk = (unsigned)f2bf(w2r[2 * ii]) |
                              ((unsigned)f2bf(w2r[2 * ii + 1]) << 16);
                *(unsigned*)&s_w12[6656 + o * HS + part * 16 + 2 * ii] = pk;
            }
        }

        // ---- busy-wait: high-duty packed-f32 FMA burn (SCLK probe v2) ----
        {
            f32x2 c0, c1, c2, c3, ka, kb;
            c0.x = 1.0f + (float)t; c0.y = 2.0f;
            c1.x = 3.0f;            c1.y = 4.0f;
            c2.x = 5.0f;            c2.y = 6.0f;
            c3.x = 7.0f;            c3.y = 8.0f;
            ka.x = 0.9999f;  ka.y = 0.99991f;
            kb.x = 1.0f;     kb.y = 1.25f;       // chains converge, no inf
            if (t < 4) {
                unsigned* sp = sel + b * NPOINT + (g << 2) + t;
                for (;;) {
                    unsigned v = __hip_atomic_load(sp, __ATOMIC_RELAXED,
                                                   __HIP_MEMORY_SCOPE_AGENT);
                    if ((v - 1u) <= 8191u) { s_sel4[t] = (int)(v - 1u); break; }
#pragma unroll
                    for (int q = 0; q < 16; ++q) {
                        c0 = c0 * ka + kb; c1 = c1 * ka + kb;
                        c2 = c2 * ka + kb; c3 = c3 * ka + kb;
                    }
                }
                __hip_atomic_fetch_add(s_ready, 1, __ATOMIC_RELAXED,
                                       __HIP_MEMORY_SCOPE_WORKGROUP);
            }
            // all waves: 256 pk-fma (~512 cy issue) between ready polls
            while (__hip_atomic_load(s_ready, __ATOMIC_RELAXED,
                                     __HIP_MEMORY_SCOPE_WORKGROUP) < 4) {
#pragma unroll
                for (int q = 0; q < 64; ++q) {
                    c0 = c0 * ka + kb; c1 = c1 * ka + kb;
                    c2 = c2 * ka + kb; c3 = c3 * ka + kb;
                }
            }
            asm volatile("" :: "v"(c0.x), "v"(c0.y), "v"(c1.x), "v"(c1.y),
                              "v"(c2.x), "v"(c2.y), "v"(c3.x), "v"(c3.y));
        }
        __syncthreads();

        // ---- ball query: wave w -> centroid s_sel4[w] ----
        {
            const int cidx = s_sel4[w];
            const float* base = xyz + (size_t)b * NN * 3;
            const float cx = base[cidx * 3 + 0];   // bit-identical to new_xyz
            const float cy = base[cidx * 3 + 1];
            const float cz = base[cidx * 3 + 2];
            const float R2 = (float)(0.4 * 0.4);   // 0.15999999642f

            int have = 0;
            for (int chunk = 0; chunk < (NN / 64) && have < NSAMPLE; ++chunk) {
                int p = (chunk << 6) + lane;
                float dx = __fsub_rn(cx, base[p * 3 + 0]);
                float dy = __fsub_rn(cy, base[p * 3 + 1]);
                float dz = __fsub_rn(cz, base[p * 3 + 2]);
                float d2 = __fadd_rn(__fadd_rn(__fmul_rn(dx, dx), __fmul_rn(dy, dy)),
                                     __fmul_rn(dz, dz));
                bool in = d2 < R2;
                unsigned long long m = __ballot(in);
                int pre = __popcll(m & ((1ull << lane) - 1ull));
                int slot = have + pre;
                if (in && slot < NSAMPLE) s_gi[w * NSAMPLE + slot] = p;
                have += (int)__popcll(m);
            }
            if (lane < NSAMPLE) {
                int first = s_gi[w * NSAMPLE];    // centroid always hits
                int v = (lane < have) ? s_gi[w * NSAMPLE + lane] : first;
                s_gi[w * NSAMPLE + lane] = v;
            }
        }
        __syncthreads();

        // ---- gather x = [feat(64) | xyz_rel(3) | zeros] in bf16 ----
        {
            int k = t >> 1, half = t & 1;
            int row = s_gi[k];
            const float4* frow =
                (const float4*)(features + ((size_t)b * NN + row) * 64) + half * 8;
            unsigned short* xr = &s_x[k * XS + half * 32];
#pragma unroll
            for (int ii = 0; ii < 8; ++ii) {
                float4 v = frow[ii];
                unsigned lo = (unsigned)f2bf(v.x) | ((unsigned)f2bf(v.y) << 16);
                unsigned hi = (unsigned)f2bf(v.z) | ((unsigned)f2bf(v.w) << 16);
                *(uint2*)(xr + ii * 4) = make_uint2(lo, hi);
            }
        }
        if (t < 128) {
            int k = t;
            int row = s_gi[k];
            int cidx = s_sel4[k >> 5];
            const float* pr = xyz + ((size_t)b * NN + row) * 3;
            const float* cr = xyz + ((size_t)b * NN + cidx) * 3;
            s_x[k * XS + 64] = f2bf(pr[0] - cr[0]);
            s_x[k * XS + 65] = f2bf(pr[1] - cr[1]);
            s_x[k * XS + 66] = f2bf(pr[2] - cr[2]);
            s_x[k * XS + 67] = 0;
            unsigned* z = (unsigned*)&s_x[k * XS + 68];
#pragma unroll
            for (int ii = 0; ii < 14; ++ii) z[ii] = 0;    // cols 68..95
        }
        __syncthreads();

        const int mbase = w * 32;

        // ---- Layer 1: [128 x 96] x [96 -> 64] ----
        floatx4 acc[2][4] = {};
        for (int kk = 0; kk < 3; ++kk) {
            short8 a0 = *(const short8*)&s_x[(mbase + col) * XS + kk * 32 + quad * 8];
            short8 a1 = *(const short8*)&s_x[(mbase + 16 + col) * XS + kk * 32 + quad * 8];
#pragma unroll
            for (int nt = 0; nt < 4; ++nt) {
                short8 bfr = *(const short8*)&s_w12[(nt * 16 + col) * XS + kk * 32 + quad * 8];
                acc[0][nt] = __builtin_amdgcn_mfma_f32_16x16x32_bf16(a0, bfr, acc[0][nt], 0, 0, 0);
                acc[1][nt] = __builtin_amdgcn_mfma_f32_16x16x32_bf16(a1, bfr, acc[1][nt], 0, 0, 0);
            }
        }
#pragma unroll
        for (int nt = 0; nt < 4; ++nt) {
            float bb = b1[nt * 16 + col];
#pragma unroll
            for (int mt = 0; mt < 2; ++mt)
#pragma unroll
                for (int r = 0; r < 4; ++r) {
                    float v = fmaxf(acc[mt][nt][r] + bb, 0.0f);
                    s_h[(mbase + mt * 16 + quad * 4 + r) * HS + nt * 16 + col] = f2bf(v);
                }
        }
        __syncthreads();

        // ---- Layer 2: [128 x 64] x [64 -> 64], h2 -> s_x region ----
        floatx4 acc2[2][4] = {};
        for (int kk = 0; kk < 2; ++kk) {
            short8 a0 = *(const short8*)&s_h[(mbase + col) * HS + kk * 32 + quad * 8];
            short8 a1 = *(const short8*)&s_h[(mbase + 16 + col) * HS + kk * 32 + quad * 8];
#pragma unroll
            for (int nt = 0; nt < 4; ++nt) {
                short8 bfr = *(const short8*)&s_w12[6656 + (nt * 16 + col) * HS + kk * 32 + quad * 8];
                acc2[0][nt] = __builtin_amdgcn_mfma_f32_16x16x32_bf16(a0, bfr, acc2[0][nt], 0, 0, 0);
                acc2[1][nt] = __builtin_amdgcn_mfma_f32_16x16x32_bf16(a1, bfr, acc2[1][nt], 0, 0, 0);
            }
        }
        unsigned short* s_h2 = s_x;  // x dead after L1
#pragma unroll
        for (int nt = 0; nt < 4; ++nt) {
            float bb = b2[nt * 16 + col];
#pragma unroll
            for (int mt = 0; mt < 2; ++mt)
#pragma unroll
                for (int r = 0; r < 4; ++r) {
                    float v = fmaxf(acc2[mt][nt][r] + bb, 0.0f);
                    s_h2[(mbase + mt * 16 + quad * 4 + r) * HS + nt * 16 + col] = f2bf(v);
                }
        }
        __syncthreads();   // h2 complete; all w2 reads done

        // ---- stage w3 [128][HS] over w1/w2 ----
        {
            int o = t >> 1, half = t & 1;
            const float* w3r = w3 + o * 64 + half * 32;
#pragma unroll
            for (int ii = 0; ii < 16; ++ii) {
                unsigned pk = (unsigned)f2bf(w3r[2 * ii]) |
                              ((unsigned)f2bf(w3r[2 * ii + 1]) << 16);
                *(unsigned*)&s_w12[o * HS + half * 32 + 2 * ii] = pk;
            }
        }
        __syncthreads();

        // ---- Layer 3: [128 x 64] x [64 -> 128], fused maxpool+bias+relu ----
        floatx4 c3[2][8] = {};
        for (int kk = 0; kk < 2; ++kk) {
            short8 a0 = *(const short8*)&s_h2[(mbase + col) * HS + kk * 32 + quad * 8];
            short8 a1 = *(const short8*)&s_h2[(mbase + 16 + col) * HS + kk * 32 + quad * 8];
#pragma unroll
            for (int nt = 0; nt < 8; ++nt) {
                short8 bfr = *(const short8*)&s_w12[(nt * 16 + col) * HS + kk * 32 + quad * 8];
                c3[0][nt] = __builtin_amdgcn_mfma_f32_16x16x32_bf16(a0, bfr, c3[0][nt], 0, 0, 0);
                c3[1][nt] = __builtin_amdgcn_mfma_f32_16x16x32_bf16(a1, bfr, c3[1][nt], 0, 0, 0);
            }
        }
        {
            int gg = (g << 2) + w;
            float* ob = out_feat + (size_t)b * (128 * 1024) + gg;
#pragma unroll
            for (int nt = 0; nt < 8; ++nt) {
                float m = fmaxf(fmaxf(fmaxf(c3[0][nt][0], c3[0][nt][1]),
                                      fmaxf(c3[0][nt][2], c3[0][nt][3])),
                                fmaxf(fmaxf(c3[1][nt][0], c3[1][nt][1]),
                                      fmaxf(c3[1][nt][2], c3[1][nt][3])));
                m = fmaxf(m, __shfl_xor(m, 16));
                m = fmaxf(m, __shfl_xor(m, 32));
                if (lane < 16) {
                    float v = fmaxf(m + b3[nt * 16 + lane], 0.0f);
                    ob[(size_t)(nt * 16 + lane) * 1024] = v;
                }
            }
        }
    }
}

extern "C" void kernel_launch(void* const* d_in, const int* in_sizes, int n_in,
                              void* d_out, int out_size, void* d_ws, size_t ws_size,
                              hipStream_t stream) {
    const float* xyz      = (const float*)d_in[0];
    const float* features = (const float*)d_in[1];
    const float* w1       = (const float*)d_in[2];
    const float* b1       = (const float*)d_in[3];
    const float* w2       = (const float*)d_in[4];
    const float* b2       = (const float*)d_in[5];
    const float* w3       = (const float*)d_in[6];
    const float* b3       = (const float*)d_in[7];

    float* out      = (float*)d_out;
    float* new_xyz  = out;                         // B*NPOINT*3
    float* out_feat = out + BB * NPOINT * 3;       // B*128*NPOINT
    unsigned* sel   = (unsigned*)d_ws;             // B*NPOINT u32; poison = not-ready

    mega_kernel<<<BB + (BB * NPOINT) / 4, 256, 0, stream>>>(
        xyz, features, w1, b1, w2, b2, w3, b3, new_xyz, out_feat, sel);
}

// Round 10
// 1010.843 us; speedup vs baseline: 1.0059x; 1.0055x over previous
//
#include <hip/hip_runtime.h>
#include <stdint.h>

#define BB 8
#define NN 8192
#define NPOINT 1024
#define NSAMPLE 32
#define XS 104   // x row stride in bf16 elems (cols: 0..63 feat, 64..66 xyz, 67..95 zero)
#define HS 72    // h / w2 / w3 row stride in bf16 elems (cols 0..63 used)

typedef short short8 __attribute__((ext_vector_type(8)));
typedef float floatx4 __attribute__((ext_vector_type(4)));
typedef float f32x2 __attribute__((ext_vector_type(2)));

__device__ __forceinline__ unsigned short f2bf(float f) {
    unsigned u = __float_as_uint(f);
    unsigned r = u + 0x7FFFu + ((u >> 16) & 1u);   // RNE to bf16
    return (unsigned short)(r >> 16);
}

__device__ __forceinline__ unsigned long long u64max(unsigned long long a,
                                                     unsigned long long b) {
    return (a > b) ? a : b;
}

template <int CTRL, int RMASK>
__device__ __forceinline__ unsigned long long dpp_max_step(unsigned long long key) {
    int lo = (int)(unsigned int)(key & 0xffffffffull);
    int hi = (int)(unsigned int)(key >> 32);
    int tlo = __builtin_amdgcn_update_dpp(0, lo, CTRL, RMASK, 0xF, true);
    int thi = __builtin_amdgcn_update_dpp(0, hi, CTRL, RMASK, 0xF, true);
    unsigned long long t = ((unsigned long long)(unsigned int)thi << 32) |
                           (unsigned long long)(unsigned int)tlo;
    return u64max(key, t);
}

__device__ __forceinline__ unsigned long long dpp_wave_max(unsigned long long key) {
    key = dpp_max_step<0x111, 0xF>(key);  // row_shr:1
    key = dpp_max_step<0x112, 0xF>(key);  // row_shr:2
    key = dpp_max_step<0x114, 0xF>(key);  // row_shr:4
    key = dpp_max_step<0x118, 0xF>(key);  // row_shr:8
    key = dpp_max_step<0x142, 0xA>(key);  // row_bcast:15
    key = dpp_max_step<0x143, 0xC>(key);  // row_bcast:31
    return key;
}

// Barrier that does NOT drain vmcnt: LDS ordering only (measured neutral vs
// __syncthreads in R11; kept because it cannot be slower).
__device__ __forceinline__ void fps_bar() {
    asm volatile("s_waitcnt lgkmcnt(0)" ::: "memory");
    __builtin_amdgcn_s_barrier();
    asm volatile("" ::: "memory");
}

// ---------------------------------------------------------------------------
// MEGA KERNEL (256-thread blocks). Blocks 0..7: FPS (one per batch, 4 waves,
// 32 pts/thread). Blocks 8..2055: consumers (b=i&7, g=i>>3), 4 centroids each:
// spin on sel[] (relaxed agent atomics; payload=idx+1), then ball query +
// bf16-MFMA MLP + maxpool, hidden behind the fps-paced wait.
//
// R16: __launch_bounds__(256, 1). FPS persistent state (px2/py2/pz2=96 +
// dist=32 = 128 regs) exceeds the 132 ArchVGPRs reported => compiler MUST be
// parking arrays in AGPRs (gfx950 unified file) and paying v_accvgpr_read/
// write on every access — the invisible per-iteration tax that explains the
// whole R8-R15 ledger (packed-f32 null, R12 catastrophe). Both block types
// are LDS-bound to 1 block/CU (96.5KB), so min-1-wave/EU costs zero
// occupancy and unlocks the full register budget. R15's burn reverted to
// the neutral s_sleep(32) wait.
// Pre-committed read: VGPR>=170 & ~750-870us => tax was real;
// VGPR>=170 & ~944us => tax off critical path, structural floor next;
// VGPR ~132 => compiler was never constrained, theory dead.
// ---------------------------------------------------------------------------
__global__ __launch_bounds__(256, 1) void mega_kernel(
    const float* __restrict__ xyz, const float* __restrict__ features,
    const float* __restrict__ w1, const float* __restrict__ b1,
    const float* __restrict__ w2, const float* __restrict__ b2,
    const float* __restrict__ w3, const float* __restrict__ b3,
    float* __restrict__ new_xyz, float* __restrict__ out_feat,
    unsigned* __restrict__ sel) {
    __shared__ __align__(16) char smem[98432];

    const int t = threadIdx.x;
    const int lane = t & 63;

    if (blockIdx.x < BB) {
        // =================== FPS (4 waves, u64-key DPP reduce) ==============
#pragma clang fp contract(off)
        const int b = blockIdx.x;
        float* sxyz = (float*)smem;                              // [8192][3]
        unsigned long long* wred = (unsigned long long*)(smem + 98304); // [2][4]
        const int wv = t >> 6;
        const float* base = xyz + (size_t)b * NN * 3;
        unsigned* selb = sel + b * NPOINT;

        f32x2 px2[16], py2[16], pz2[16];
        float dist[32];
#pragma unroll
        for (int i = 0; i < 32; ++i) {
            int p = t + (i << 8);               // coalesced glb; LDS 2-way/bank
            float x = base[p * 3 + 0];
            float y = base[p * 3 + 1];
            float z = base[p * 3 + 2];
            sxyz[p * 3 + 0] = x; sxyz[p * 3 + 1] = y; sxyz[p * 3 + 2] = z;
            if (i & 1) { px2[i >> 1].y = x; py2[i >> 1].y = y; pz2[i >> 1].y = z; }
            else       { px2[i >> 1].x = x; py2[i >> 1].x = y; pz2[i >> 1].x = z; }
            dist[i] = 1e10f;                    // f32(10000000000.0) exact
        }
        __syncthreads();

        float lx = sxyz[0], ly = sxyz[1], lz = sxyz[2];
        float* outb = new_xyz + (size_t)b * NPOINT * 3;
        if (t == 0) {
            outb[0] = lx; outb[1] = ly; outb[2] = lz;
            __hip_atomic_store(&selb[0], 1u, __ATOMIC_RELAXED,
                               __HIP_MEMORY_SCOPE_AGENT);
        }

        for (int j = 1; j < NPOINT; ++j) {
            float bd0 = -1.0f, bd1 = -1.0f;
            int bi0 = 0, bi1 = 16;
            f32x2 lx2; lx2.x = lx; lx2.y = lx;
            f32x2 ly2; ly2.x = ly; ly2.y = ly;
            f32x2 lz2; lz2.x = lz; lz2.y = lz;
#pragma unroll
            for (int jj = 0; jj < 16; ++jj) {
                // packed (v_pk_add_f32 / v_pk_mul_f32, IEEE RN, no contraction)
                f32x2 dx = px2[jj] - lx2;
                f32x2 dy = py2[jj] - ly2;
                f32x2 dz = pz2[jj] - lz2;
                f32x2 xx = dx * dx;
                f32x2 yy = dy * dy;
                f32x2 zz = dz * dz;
                f32x2 s1 = xx + yy;
                f32x2 d2 = s1 + zz;
                float d0 = fminf(dist[2 * jj], d2.x);
                dist[2 * jj] = d0;
                float d1 = fminf(dist[2 * jj + 1], d2.y);
                dist[2 * jj + 1] = d1;
                // within-pair argmax: >= prefers even slot (lower point idx)
                bool ge = d0 >= d1;
                float pm = ge ? d0 : d1;
                int pi = ge ? (2 * jj) : (2 * jj + 1);
                if (jj < 8) {            // chain A: elems 0..15 (lower indices)
                    bool gt = pm > bd0;
                    bd0 = gt ? pm : bd0;
                    bi0 = gt ? pi : bi0;
                } else {                 // chain B: elems 16..31
                    bool gt = pm > bd1;
                    bd1 = gt ? pm : bd1;
                    bi1 = gt ? pi : bi1;
                }
            }
            unsigned long long key0 =
                ((unsigned long long)__float_as_uint(bd0) << 32) |
                (unsigned long long)(~(unsigned int)(t + (bi0 << 8)));
            unsigned long long key1 =
                ((unsigned long long)__float_as_uint(bd1) << 32) |
                (unsigned long long)(~(unsigned int)(t + (bi1 << 8)));
            unsigned long long key = u64max(key0, key1);
            key = dpp_wave_max(key);
            if (lane == 63) wred[(j & 1) * 4 + wv] = key;
            fps_bar();
            int cur;
            {
                const unsigned long long* wr = &wred[(j & 1) * 4];
                ulonglong2 p01 = *(const ulonglong2*)&wr[0];
                ulonglong2 p23 = *(const ulonglong2*)&wr[2];
                unsigned long long m = u64max(u64max(p01.x, p01.y),
                                              u64max(p23.x, p23.y));
                cur = (int)(~(unsigned int)(m & 0xffffffffull));
            }
            {   // one contiguous 12B broadcast read (wave-uniform address)
                const float* cp = &sxyz[cur * 3];
                float3 c = *(const float3*)cp;
                lx = c.x; ly = c.y; lz = c.z;
            }
            if (t == 0) {
                outb[j * 3 + 0] = lx;
                outb[j * 3 + 1] = ly;
                outb[j * 3 + 2] = lz;
                __hip_atomic_store(&selb[j], (unsigned)(cur + 1),
                                   __ATOMIC_RELAXED, __HIP_MEMORY_SCOPE_AGENT);
            }
        }
    } else {
        // =================== consumer: ballq + MFMA MLP =====================
        const int i = blockIdx.x - BB;
        const int b = i & 7;                   // batch
        const int g = i >> 3;                  // centroid group (4 centroids)
        unsigned short* s_x = (unsigned short*)smem;            // 128*XS
        unsigned short* s_h = (unsigned short*)(smem + 26624);  // 128*HS
        unsigned short* s_w12 = (unsigned short*)(smem + 45056);// 11264 elems
        int* s_gi = (int*)(smem + 67584);                       // 128
        int* s_sel4 = (int*)(smem + 68096);                     // 4

        const int w = t >> 6;
        const int col = lane & 15;
        const int quad = lane >> 4;

        // ---- stage w1, w2 (independent of fps progress) ----
        {
            int o = t >> 2, part = t & 3;
            const float* w1r = w1 + o * 67;
#pragma unroll
            for (int ii = 0; ii < 26; ++ii) {
                int c = part * 26 + ii;
                float v = 0.0f;
                if (c < 64) v = w1r[3 + c];           // permuted: feats first
                else if (c < 67) v = w1r[c - 64];     // then xyz cols
                s_w12[o * XS + c] = f2bf(v);
            }
            const float* w2r = w2 + o * 64 + part * 16;
#pragma unroll
            for (int ii = 0; ii < 8; ++ii) {
                unsigned pk = (unsigned)f2bf(w2r[2 * ii]) |
                              ((unsigned)f2bf(w2r[2 * ii + 1]) << 16);
                *(unsigned*)&s_w12[6656 + o * HS + part * 16 + 2 * ii] = pk;
            }
        }

        // ---- spin for the 4 centroid indices ----
        if (t < 4) {
            unsigned* sp = sel + b * NPOINT + (g << 2) + t;
            unsigned v;
            while ((( v = __hip_atomic_load(sp, __ATOMIC_RELAXED,
                                            __HIP_MEMORY_SCOPE_AGENT)) - 1u) > 8191u)
                __builtin_amdgcn_s_sleep(32);
            s_sel4[t] = (int)(v - 1u);
        }
        __syncthreads();

        // ---- ball query: wave w -> centroid s_sel4[w] ----
        {
            const int cidx = s_sel4[w];
            const float* base = xyz + (size_t)b * NN * 3;
            const float cx = base[cidx * 3 + 0];   // bit-identical to new_xyz
            const float cy = base[cidx * 3 + 1];
            const float cz = base[cidx * 3 + 2];
            const float R2 = (float)(0.4 * 0.4);   // 0.15999999642f

            int have = 0;
            for (int chunk = 0; chunk < (NN / 64) && have < NSAMPLE; ++chunk) {
                int p = (chunk << 6) + lane;
                float dx = __fsub_rn(cx, base[p * 3 + 0]);
                float dy = __fsub_rn(cy, base[p * 3 + 1]);
                float dz = __fsub_rn(cz, base[p * 3 + 2]);
                float d2 = __fadd_rn(__fadd_rn(__fmul_rn(dx, dx), __fmul_rn(dy, dy)),
                                     __fmul_rn(dz, dz));
                bool in = d2 < R2;
                unsigned long long m = __ballot(in);
                int pre = __popcll(m & ((1ull << lane) - 1ull));
                int slot = have + pre;
                if (in && slot < NSAMPLE) s_gi[w * NSAMPLE + slot] = p;
                have += (int)__popcll(m);
            }
            if (lane < NSAMPLE) {
                int first = s_gi[w * NSAMPLE];    // centroid always hits
                int v = (lane < have) ? s_gi[w * NSAMPLE + lane] : first;
                s_gi[w * NSAMPLE + lane] = v;
            }
        }
        __syncthreads();

        // ---- gather x = [feat(64) | xyz_rel(3) | zeros] in bf16 ----
        {
            int k = t >> 1, half = t & 1;
            int row = s_gi[k];
            const float4* frow =
                (const float4*)(features + ((size_t)b * NN + row) * 64) + half * 8;
            unsigned short* xr = &s_x[k * XS + half * 32];
#pragma unroll
            for (int ii = 0; ii < 8; ++ii) {
                float4 v = frow[ii];
                unsigned lo = (unsigned)f2bf(v.x) | ((unsigned)f2bf(v.y) << 16);
                unsigned hi = (unsigned)f2bf(v.z) | ((unsigned)f2bf(v.w) << 16);
                *(uint2*)(xr + ii * 4) = make_uint2(lo, hi);
            }
        }
        if (t < 128) {
            int k = t;
            int row = s_gi[k];
            int cidx = s_sel4[k >> 5];
            const float* pr = xyz + ((size_t)b * NN + row) * 3;
            const float* cr = xyz + ((size_t)b * NN + cidx) * 3;
            s_x[k * XS + 64] = f2bf(pr[0] - cr[0]);
            s_x[k * XS + 65] = f2bf(pr[1] - cr[1]);
            s_x[k * XS + 66] = f2bf(pr[2] - cr[2]);
            s_x[k * XS + 67] = 0;
            unsigned* z = (unsigned*)&s_x[k * XS + 68];
#pragma unroll
            for (int ii = 0; ii < 14; ++ii) z[ii] = 0;    // cols 68..95
        }
        __syncthreads();

        const int mbase = w * 32;

        // ---- Layer 1: [128 x 96] x [96 -> 64] ----
        floatx4 acc[2][4] = {};
        for (int kk = 0; kk < 3; ++kk) {
            short8 a0 = *(const short8*)&s_x[(mbase + col) * XS + kk * 32 + quad * 8];
            short8 a1 = *(const short8*)&s_x[(mbase + 16 + col) * XS + kk * 32 + quad * 8];
#pragma unroll
            for (int nt = 0; nt < 4; ++nt) {
                short8 bfr = *(const short8*)&s_w12[(nt * 16 + col) * XS + kk * 32 + quad * 8];
                acc[0][nt] = __builtin_amdgcn_mfma_f32_16x16x32_bf16(a0, bfr, acc[0][nt], 0, 0, 0);
                acc[1][nt] = __builtin_amdgcn_mfma_f32_16x16x32_bf16(a1, bfr, acc[1][nt], 0, 0, 0);
            }
        }
#pragma unroll
        for (int nt = 0; nt < 4; ++nt) {
            float bb = b1[nt * 16 + col];
#pragma unroll
            for (int mt = 0; mt < 2; ++mt)
#pragma unroll
                for (int r = 0; r < 4; ++r) {
                    float v = fmaxf(acc[mt][nt][r] + bb, 0.0f);
                    s_h[(mbase + mt * 16 + quad * 4 + r) * HS + nt * 16 + col] = f2bf(v);
                }
        }
        __syncthreads();

        // ---- Layer 2: [128 x 64] x [64 -> 64], h2 -> s_x region ----
        floatx4 acc2[2][4] = {};
        for (int kk = 0; kk < 2; ++kk) {
            short8 a0 = *(const short8*)&s_h[(mbase + col) * HS + kk * 32 + quad * 8];
            short8 a1 = *(const short8*)&s_h[(mbase + 16 + col) * HS + kk * 32 + quad * 8];
#pragma unroll
            for (int nt = 0; nt < 4; ++nt) {
                short8 bfr = *(const short8*)&s_w12[6656 + (nt * 16 + col) * HS + kk * 32 + quad * 8];
                acc2[0][nt] = __builtin_amdgcn_mfma_f32_16x16x32_bf16(a0, bfr, acc2[0][nt], 0, 0, 0);
                acc2[1][nt] = __builtin_amdgcn_mfma_f32_16x16x32_bf16(a1, bfr, acc2[1][nt], 0, 0, 0);
            }
        }
        unsigned short* s_h2 = s_x;  // x dead after L1
#pragma unroll
        for (int nt = 0; nt < 4; ++nt) {
            float bb = b2[nt * 16 + col];
#pragma unroll
            for (int mt = 0; mt < 2; ++mt)
#pragma unroll
                for (int r = 0; r < 4; ++r) {
                    float v = fmaxf(acc2[mt][nt][r] + bb, 0.0f);
                    s_h2[(mbase + mt * 16 + quad * 4 + r) * HS + nt * 16 + col] = f2bf(v);
                }
        }
        __syncthreads();   // h2 complete; all w2 reads done

        // ---- stage w3 [128][HS] over w1/w2 ----
        {
            int o = t >> 1, half = t & 1;
            const float* w3r = w3 + o * 64 + half * 32;
#pragma unroll
            for (int ii = 0; ii < 16; ++ii) {
                unsigned pk = (unsigned)f2bf(w3r[2 * ii]) |
                              ((unsigned)f2bf(w3r[2 * ii + 1]) << 16);
                *(unsigned*)&s_w12[o * HS + half * 32 + 2 * ii] = pk;
            }
        }
        __syncthreads();

        // ---- Layer 3: [128 x 64] x [64 -> 128], fused maxpool+bias+relu ----
        floatx4 c3[2][8] = {};
        for (int kk = 0; kk < 2; ++kk) {
            short8 a0 = *(const short8*)&s_h2[(mbase + col) * HS + kk * 32 + quad * 8];
            short8 a1 = *(const short8*)&s_h2[(mbase + 16 + col) * HS + kk * 32 + quad * 8];
#pragma unroll
            for (int nt = 0; nt < 8; ++nt) {
                short8 bfr = *(const short8*)&s_w12[(nt * 16 + col) * HS + kk * 32 + quad * 8];
                c3[0][nt] = __builtin_amdgcn_mfma_f32_16x16x32_bf16(a0, bfr, c3[0][nt], 0, 0, 0);
                c3[1][nt] = __builtin_amdgcn_mfma_f32_16x16x32_bf16(a1, bfr, c3[1][nt], 0, 0, 0);
            }
        }
        {
            int gg = (g << 2) + w;
            float* ob = out_feat + (size_t)b * (128 * 1024) + gg;
#pragma unroll
            for (int nt = 0; nt < 8; ++nt) {
                float m = fmaxf(fmaxf(fmaxf(c3[0][nt][0], c3[0][nt][1]),
                                      fmaxf(c3[0][nt][2], c3[0][nt][3])),
                                fmaxf(fmaxf(c3[1][nt][0], c3[1][nt][1]),
                                      fmaxf(c3[1][nt][2], c3[1][nt][3])));
                m = fmaxf(m, __shfl_xor(m, 16));
                m = fmaxf(m, __shfl_xor(m, 32));
                if (lane < 16) {
                    float v = fmaxf(m + b3[nt * 16 + lane], 0.0f);
                    ob[(size_t)(nt * 16 + lane) * 1024] = v;
                }
            }
        }
    }
}

extern "C" void kernel_launch(void* const* d_in, const int* in_sizes, int n_in,
                              void* d_out, int out_size, void* d_ws, size_t ws_size,
                              hipStream_t stream) {
    const float* xyz      = (const float*)d_in[0];
    const float* features = (const float*)d_in[1];
    const float* w1       = (const float*)d_in[2];
    const float* b1       = (const float*)d_in[3];
    const float* w2       = (const float*)d_in[4];
    const float* b2       = (const float*)d_in[5];
    const float* w3       = (const float*)d_in[6];
    const float* b3       = (const float*)d_in[7];

    float* out      = (float*)d_out;
    float* new_xyz  = out;                         // B*NPOINT*3
    float* out_feat = out + BB * NPOINT * 3;       // B*128*NPOINT
    unsigned* sel   = (unsigned*)d_ws;             // B*NPOINT u32; poison = not-ready

    mega_kernel<<<BB + (BB * NPOINT) / 4, 256, 0, stream>>>(
        xyz, features, w1, b1, w2, b2, w3, b3, new_xyz, out_feat, sel);
}

// Round 11
// 1009.259 us; speedup vs baseline: 1.0075x; 1.0016x over previous
//
#include <hip/hip_runtime.h>
#include <stdint.h>

#define BB 8
#define NN 8192
#define NPOINT 1024
#define NSAMPLE 32
#define XS 104   // x row stride in bf16 elems (cols: 0..63 feat, 64..66 xyz, 67..95 zero)
#define HS 72    // h / w2 / w3 row stride in bf16 elems (cols 0..63 used)

typedef short short8 __attribute__((ext_vector_type(8)));
typedef float floatx4 __attribute__((ext_vector_type(4)));
typedef float f32x2 __attribute__((ext_vector_type(2)));

__device__ __forceinline__ unsigned short f2bf(float f) {
    unsigned u = __float_as_uint(f);
    unsigned r = u + 0x7FFFu + ((u >> 16) & 1u);   // RNE to bf16
    return (unsigned short)(r >> 16);
}

__device__ __forceinline__ unsigned long long u64max(unsigned long long a,
                                                     unsigned long long b) {
    return (a > b) ? a : b;
}

template <int CTRL, int RMASK>
__device__ __forceinline__ unsigned long long dpp_max_step(unsigned long long key) {
    int lo = (int)(unsigned int)(key & 0xffffffffull);
    int hi = (int)(unsigned int)(key >> 32);
    int tlo = __builtin_amdgcn_update_dpp(0, lo, CTRL, RMASK, 0xF, true);
    int thi = __builtin_amdgcn_update_dpp(0, hi, CTRL, RMASK, 0xF, true);
    unsigned long long t = ((unsigned long long)(unsigned int)thi << 32) |
                           (unsigned long long)(unsigned int)tlo;
    return u64max(key, t);
}

__device__ __forceinline__ unsigned long long dpp_wave_max(unsigned long long key) {
    key = dpp_max_step<0x111, 0xF>(key);  // row_shr:1
    key = dpp_max_step<0x112, 0xF>(key);  // row_shr:2
    key = dpp_max_step<0x114, 0xF>(key);  // row_shr:4
    key = dpp_max_step<0x118, 0xF>(key);  // row_shr:8
    key = dpp_max_step<0x142, 0xA>(key);  // row_bcast:15
    key = dpp_max_step<0x143, 0xC>(key);  // row_bcast:31
    return key;
}

// Barrier that does NOT drain vmcnt: LDS ordering only (measured neutral vs
// __syncthreads in R11; kept because it cannot be slower).
__device__ __forceinline__ void fps_bar() {
    asm volatile("s_waitcnt lgkmcnt(0)" ::: "memory");
    __builtin_amdgcn_s_barrier();
    asm volatile("" ::: "memory");
}

// ---------------------------------------------------------------------------
// MEGA KERNEL (256-thread blocks). Blocks 0..7: FPS (one per batch, 4 waves,
// 32 pts/thread). Blocks 8..2055: consumers (b=i&7, g=i>>3), 4 centroids each:
// spin on sel[] (relaxed agent atomics; payload=idx+1), then ball query +
// bf16-MFMA MLP + maxpool, hidden behind the fps-paced wait.
//
// R17 = FINAL CHAMPION (R13 config, 943us). Session ledger: packed-f32 null
// (R8), 8-wave -150us (R9), split-key reduce -94us (R10), coords-through-
// reduce -200us (R12), lgkm-only barrier null (R11), interleaved sxyz +
// s_sleep(32) null (R13), VALU-burn clock probes null/negative (R14/R15),
// launch_bounds(256,1) null with VGPR unchanged at 132 (R16). The pace is
// the FPS serial tail (DPP reduce + barrier + two dependent LDS round trips
// ~2180 cy/iter x 1023 iters) at 1-wave/SIMD occupancy — a latency floor
// forced by the algorithm's strict sequential dependence and bit-exactness,
// not a memory/compute roofline. Removing work never helped; adding serial
// work always hurt proportional to dependent latency.
// ---------------------------------------------------------------------------
__global__ __launch_bounds__(256) void mega_kernel(
    const float* __restrict__ xyz, const float* __restrict__ features,
    const float* __restrict__ w1, const float* __restrict__ b1,
    const float* __restrict__ w2, const float* __restrict__ b2,
    const float* __restrict__ w3, const float* __restrict__ b3,
    float* __restrict__ new_xyz, float* __restrict__ out_feat,
    unsigned* __restrict__ sel) {
    __shared__ __align__(16) char smem[98432];

    const int t = threadIdx.x;
    const int lane = t & 63;

    if (blockIdx.x < BB) {
        // =================== FPS (4 waves, u64-key DPP reduce) ==============
#pragma clang fp contract(off)
        const int b = blockIdx.x;
        float* sxyz = (float*)smem;                              // [8192][3]
        unsigned long long* wred = (unsigned long long*)(smem + 98304); // [2][4]
        const int wv = t >> 6;
        const float* base = xyz + (size_t)b * NN * 3;
        unsigned* selb = sel + b * NPOINT;

        f32x2 px2[16], py2[16], pz2[16];
        float dist[32];
#pragma unroll
        for (int i = 0; i < 32; ++i) {
            int p = t + (i << 8);               // coalesced glb; LDS 2-way/bank
            float x = base[p * 3 + 0];
            float y = base[p * 3 + 1];
            float z = base[p * 3 + 2];
            sxyz[p * 3 + 0] = x; sxyz[p * 3 + 1] = y; sxyz[p * 3 + 2] = z;
            if (i & 1) { px2[i >> 1].y = x; py2[i >> 1].y = y; pz2[i >> 1].y = z; }
            else       { px2[i >> 1].x = x; py2[i >> 1].x = y; pz2[i >> 1].x = z; }
            dist[i] = 1e10f;                    // f32(10000000000.0) exact
        }
        __syncthreads();

        float lx = sxyz[0], ly = sxyz[1], lz = sxyz[2];
        float* outb = new_xyz + (size_t)b * NPOINT * 3;
        if (t == 0) {
            outb[0] = lx; outb[1] = ly; outb[2] = lz;
            __hip_atomic_store(&selb[0], 1u, __ATOMIC_RELAXED,
                               __HIP_MEMORY_SCOPE_AGENT);
        }

        for (int j = 1; j < NPOINT; ++j) {
            float bd0 = -1.0f, bd1 = -1.0f;
            int bi0 = 0, bi1 = 16;
            f32x2 lx2; lx2.x = lx; lx2.y = lx;
            f32x2 ly2; ly2.x = ly; ly2.y = ly;
            f32x2 lz2; lz2.x = lz; lz2.y = lz;
#pragma unroll
            for (int jj = 0; jj < 16; ++jj) {
                // packed (v_pk_add_f32 / v_pk_mul_f32, IEEE RN, no contraction)
                f32x2 dx = px2[jj] - lx2;
                f32x2 dy = py2[jj] - ly2;
                f32x2 dz = pz2[jj] - lz2;
                f32x2 xx = dx * dx;
                f32x2 yy = dy * dy;
                f32x2 zz = dz * dz;
                f32x2 s1 = xx + yy;
                f32x2 d2 = s1 + zz;
                float d0 = fminf(dist[2 * jj], d2.x);
                dist[2 * jj] = d0;
                float d1 = fminf(dist[2 * jj + 1], d2.y);
                dist[2 * jj + 1] = d1;
                // within-pair argmax: >= prefers even slot (lower point idx)
                bool ge = d0 >= d1;
                float pm = ge ? d0 : d1;
                int pi = ge ? (2 * jj) : (2 * jj + 1);
                if (jj < 8) {            // chain A: elems 0..15 (lower indices)
                    bool gt = pm > bd0;
                    bd0 = gt ? pm : bd0;
                    bi0 = gt ? pi : bi0;
                } else {                 // chain B: elems 16..31
                    bool gt = pm > bd1;
                    bd1 = gt ? pm : bd1;
                    bi1 = gt ? pi : bi1;
                }
            }
            unsigned long long key0 =
                ((unsigned long long)__float_as_uint(bd0) << 32) |
                (unsigned long long)(~(unsigned int)(t + (bi0 << 8)));
            unsigned long long key1 =
                ((unsigned long long)__float_as_uint(bd1) << 32) |
                (unsigned long long)(~(unsigned int)(t + (bi1 << 8)));
            unsigned long long key = u64max(key0, key1);
            key = dpp_wave_max(key);
            if (lane == 63) wred[(j & 1) * 4 + wv] = key;
            fps_bar();
            int cur;
            {
                const unsigned long long* wr = &wred[(j & 1) * 4];
                ulonglong2 p01 = *(const ulonglong2*)&wr[0];
                ulonglong2 p23 = *(const ulonglong2*)&wr[2];
                unsigned long long m = u64max(u64max(p01.x, p01.y),
                                              u64max(p23.x, p23.y));
                cur = (int)(~(unsigned int)(m & 0xffffffffull));
            }
            {   // one contiguous 12B broadcast read (wave-uniform address)
                const float* cp = &sxyz[cur * 3];
                float3 c = *(const float3*)cp;
                lx = c.x; ly = c.y; lz = c.z;
            }
            if (t == 0) {
                outb[j * 3 + 0] = lx;
                outb[j * 3 + 1] = ly;
                outb[j * 3 + 2] = lz;
                __hip_atomic_store(&selb[j], (unsigned)(cur + 1),
                                   __ATOMIC_RELAXED, __HIP_MEMORY_SCOPE_AGENT);
            }
        }
    } else {
        // =================== consumer: ballq + MFMA MLP =====================
        const int i = blockIdx.x - BB;
        const int b = i & 7;                   // batch
        const int g = i >> 3;                  // centroid group (4 centroids)
        unsigned short* s_x = (unsigned short*)smem;            // 128*XS
        unsigned short* s_h = (unsigned short*)(smem + 26624);  // 128*HS
        unsigned short* s_w12 = (unsigned short*)(smem + 45056);// 11264 elems
        int* s_gi = (int*)(smem + 67584);                       // 128
        int* s_sel4 = (int*)(smem + 68096);                     // 4

        const int w = t >> 6;
        const int col = lane & 15;
        const int quad = lane >> 4;

        // ---- stage w1, w2 (independent of fps progress) ----
        {
            int o = t >> 2, part = t & 3;
            const float* w1r = w1 + o * 67;
#pragma unroll
            for (int ii = 0; ii < 26; ++ii) {
                int c = part * 26 + ii;
                float v = 0.0f;
                if (c < 64) v = w1r[3 + c];           // permuted: feats first
                else if (c < 67) v = w1r[c - 64];     // then xyz cols
                s_w12[o * XS + c] = f2bf(v);
            }
            const float* w2r = w2 + o * 64 + part * 16;
#pragma unroll
            for (int ii = 0; ii < 8; ++ii) {
                unsigned pk = (unsigned)f2bf(w2r[2 * ii]) |
                              ((unsigned)f2bf(w2r[2 * ii + 1]) << 16);
                *(unsigned*)&s_w12[6656 + o * HS + part * 16 + 2 * ii] = pk;
            }
        }

        // ---- spin for the 4 centroid indices ----
        if (t < 4) {
            unsigned* sp = sel + b * NPOINT + (g << 2) + t;
            unsigned v;
            while ((( v = __hip_atomic_load(sp, __ATOMIC_RELAXED,
                                            __HIP_MEMORY_SCOPE_AGENT)) - 1u) > 8191u)
                __builtin_amdgcn_s_sleep(32);
            s_sel4[t] = (int)(v - 1u);
        }
        __syncthreads();

        // ---- ball query: wave w -> centroid s_sel4[w] ----
        {
            const int cidx = s_sel4[w];
            const float* base = xyz + (size_t)b * NN * 3;
            const float cx = base[cidx * 3 + 0];   // bit-identical to new_xyz
            const float cy = base[cidx * 3 + 1];
            const float cz = base[cidx * 3 + 2];
            const float R2 = (float)(0.4 * 0.4);   // 0.15999999642f

            int have = 0;
            for (int chunk = 0; chunk < (NN / 64) && have < NSAMPLE; ++chunk) {
                int p = (chunk << 6) + lane;
                float dx = __fsub_rn(cx, base[p * 3 + 0]);
                float dy = __fsub_rn(cy, base[p * 3 + 1]);
                float dz = __fsub_rn(cz, base[p * 3 + 2]);
                float d2 = __fadd_rn(__fadd_rn(__fmul_rn(dx, dx), __fmul_rn(dy, dy)),
                                     __fmul_rn(dz, dz));
                bool in = d2 < R2;
                unsigned long long m = __ballot(in);
                int pre = __popcll(m & ((1ull << lane) - 1ull));
                int slot = have + pre;
                if (in && slot < NSAMPLE) s_gi[w * NSAMPLE + slot] = p;
                have += (int)__popcll(m);
            }
            if (lane < NSAMPLE) {
                int first = s_gi[w * NSAMPLE];    // centroid always hits
                int v = (lane < have) ? s_gi[w * NSAMPLE + lane] : first;
                s_gi[w * NSAMPLE + lane] = v;
            }
        }
        __syncthreads();

        // ---- gather x = [feat(64) | xyz_rel(3) | zeros] in bf16 ----
        {
            int k = t >> 1, half = t & 1;
            int row = s_gi[k];
            const float4* frow =
                (const float4*)(features + ((size_t)b * NN + row) * 64) + half * 8;
            unsigned short* xr = &s_x[k * XS + half * 32];
#pragma unroll
            for (int ii = 0; ii < 8; ++ii) {
                float4 v = frow[ii];
                unsigned lo = (unsigned)f2bf(v.x) | ((unsigned)f2bf(v.y) << 16);
                unsigned hi = (unsigned)f2bf(v.z) | ((unsigned)f2bf(v.w) << 16);
                *(uint2*)(xr + ii * 4) = make_uint2(lo, hi);
            }
        }
        if (t < 128) {
            int k = t;
            int row = s_gi[k];
            int cidx = s_sel4[k >> 5];
            const float* pr = xyz + ((size_t)b * NN + row) * 3;
            const float* cr = xyz + ((size_t)b * NN + cidx) * 3;
            s_x[k * XS + 64] = f2bf(pr[0] - cr[0]);
            s_x[k * XS + 65] = f2bf(pr[1] - cr[1]);
            s_x[k * XS + 66] = f2bf(pr[2] - cr[2]);
            s_x[k * XS + 67] = 0;
            unsigned* z = (unsigned*)&s_x[k * XS + 68];
#pragma unroll
            for (int ii = 0; ii < 14; ++ii) z[ii] = 0;    // cols 68..95
        }
        __syncthreads();

        const int mbase = w * 32;

        // ---- Layer 1: [128 x 96] x [96 -> 64] ----
        floatx4 acc[2][4] = {};
        for (int kk = 0; kk < 3; ++kk) {
            short8 a0 = *(const short8*)&s_x[(mbase + col) * XS + kk * 32 + quad * 8];
            short8 a1 = *(const short8*)&s_x[(mbase + 16 + col) * XS + kk * 32 + quad * 8];
#pragma unroll
            for (int nt = 0; nt < 4; ++nt) {
                short8 bfr = *(const short8*)&s_w12[(nt * 16 + col) * XS + kk * 32 + quad * 8];
                acc[0][nt] = __builtin_amdgcn_mfma_f32_16x16x32_bf16(a0, bfr, acc[0][nt], 0, 0, 0);
                acc[1][nt] = __builtin_amdgcn_mfma_f32_16x16x32_bf16(a1, bfr, acc[1][nt], 0, 0, 0);
            }
        }
#pragma unroll
        for (int nt = 0; nt < 4; ++nt) {
            float bb = b1[nt * 16 + col];
#pragma unroll
            for (int mt = 0; mt < 2; ++mt)
#pragma unroll
                for (int r = 0; r < 4; ++r) {
                    float v = fmaxf(acc[mt][nt][r] + bb, 0.0f);
                    s_h[(mbase + mt * 16 + quad * 4 + r) * HS + nt * 16 + col] = f2bf(v);
                }
        }
        __syncthreads();

        // ---- Layer 2: [128 x 64] x [64 -> 64], h2 -> s_x region ----
        floatx4 acc2[2][4] = {};
        for (int kk = 0; kk < 2; ++kk) {
            short8 a0 = *(const short8*)&s_h[(mbase + col) * HS + kk * 32 + quad * 8];
            short8 a1 = *(const short8*)&s_h[(mbase + 16 + col) * HS + kk * 32 + quad * 8];
#pragma unroll
            for (int nt = 0; nt < 4; ++nt) {
                short8 bfr = *(const short8*)&s_w12[6656 + (nt * 16 + col) * HS + kk * 32 + quad * 8];
                acc2[0][nt] = __builtin_amdgcn_mfma_f32_16x16x32_bf16(a0, bfr, acc2[0][nt], 0, 0, 0);
                acc2[1][nt] = __builtin_amdgcn_mfma_f32_16x16x32_bf16(a1, bfr, acc2[1][nt], 0, 0, 0);
            }
        }
        unsigned short* s_h2 = s_x;  // x dead after L1
#pragma unroll
        for (int nt = 0; nt < 4; ++nt) {
            float bb = b2[nt * 16 + col];
#pragma unroll
            for (int mt = 0; mt < 2; ++mt)
#pragma unroll
                for (int r = 0; r < 4; ++r) {
                    float v = fmaxf(acc2[mt][nt][r] + bb, 0.0f);
                    s_h2[(mbase + mt * 16 + quad * 4 + r) * HS + nt * 16 + col] = f2bf(v);
                }
        }
        __syncthreads();   // h2 complete; all w2 reads done

        // ---- stage w3 [128][HS] over w1/w2 ----
        {
            int o = t >> 1, half = t & 1;
            const float* w3r = w3 + o * 64 + half * 32;
#pragma unroll
            for (int ii = 0; ii < 16; ++ii) {
                unsigned pk = (unsigned)f2bf(w3r[2 * ii]) |
                              ((unsigned)f2bf(w3r[2 * ii + 1]) << 16);
                *(unsigned*)&s_w12[o * HS + half * 32 + 2 * ii] = pk;
            }
        }
        __syncthreads();

        // ---- Layer 3: [128 x 64] x [64 -> 128], fused maxpool+bias+relu ----
        floatx4 c3[2][8] = {};
        for (int kk = 0; kk < 2; ++kk) {
            short8 a0 = *(const short8*)&s_h2[(mbase + col) * HS + kk * 32 + quad * 8];
            short8 a1 = *(const short8*)&s_h2[(mbase + 16 + col) * HS + kk * 32 + quad * 8];
#pragma unroll
            for (int nt = 0; nt < 8; ++nt) {
                short8 bfr = *(const short8*)&s_w12[(nt * 16 + col) * HS + kk * 32 + quad * 8];
                c3[0][nt] = __builtin_amdgcn_mfma_f32_16x16x32_bf16(a0, bfr, c3[0][nt], 0, 0, 0);
                c3[1][nt] = __builtin_amdgcn_mfma_f32_16x16x32_bf16(a1, bfr, c3[1][nt], 0, 0, 0);
            }
        }
        {
            int gg = (g << 2) + w;
            float* ob = out_feat + (size_t)b * (128 * 1024) + gg;
#pragma unroll
            for (int nt = 0; nt < 8; ++nt) {
                float m = fmaxf(fmaxf(fmaxf(c3[0][nt][0], c3[0][nt][1]),
                                      fmaxf(c3[0][nt][2], c3[0][nt][3])),
                                fmaxf(fmaxf(c3[1][nt][0], c3[1][nt][1]),
                                      fmaxf(c3[1][nt][2], c3[1][nt][3])));
                m = fmaxf(m, __shfl_xor(m, 16));
                m = fmaxf(m, __shfl_xor(m, 32));
                if (lane < 16) {
                    float v = fmaxf(m + b3[nt * 16 + lane], 0.0f);
                    ob[(size_t)(nt * 16 + lane) * 1024] = v;
                }
            }
        }
    }
}

extern "C" void kernel_launch(void* const* d_in, const int* in_sizes, int n_in,
                              void* d_out, int out_size, void* d_ws, size_t ws_size,
                              hipStream_t stream) {
    const float* xyz      = (const float*)d_in[0];
    const float* features = (const float*)d_in[1];
    const float* w1       = (const float*)d_in[2];
    const float* b1       = (const float*)d_in[3];
    const float* w2       = (const float*)d_in[4];
    const float* b2       = (const float*)d_in[5];
    const float* w3       = (const float*)d_in[6];
    const float* b3       = (const float*)d_in[7];

    float* out      = (float*)d_out;
    float* new_xyz  = out;                         // B*NPOINT*3
    float* out_feat = out + BB * NPOINT * 3;       // B*128*NPOINT
    unsigned* sel   = (unsigned*)d_ws;             // B*NPOINT u32; poison = not-ready

    mega_kernel<<<BB + (BB * NPOINT) / 4, 256, 0, stream>>>(
        xyz, features, w1, b1, w2, b2, w3, b3, new_xyz, out_feat, sel);
}